// Round 1
// baseline (142.479 us; speedup 1.0000x reference)
//
#include <hip/hip_runtime.h>
#include <hip/hip_bf16.h>

typedef __bf16 bf16x8 __attribute__((ext_vector_type(8)));
typedef float f32x4 __attribute__((ext_vector_type(4)));

#define MAXD 40
#define ND 81
#define CSZ 256
#define HSZ 128
#define WSZ 416
#define KC 32
#define NCHUNK (CSZ / KC)   // 8
#define RSTRIDE 40          // bf16 elems per LDS row (32 data + 8 pad -> 80B rows, 16B aligned)
#define RPAD 48             // u-padding rows on each conceptual side (rows [0,48) and [464,512) are zero)
#define RT_ROWS 512

__global__ __launch_bounds__(256, 2)
void corr_mfma_kernel(const float* __restrict__ left,
                      const float* __restrict__ right,
                      float* __restrict__ out) {
    __shared__ __align__(16) __bf16 Lt[WSZ * RSTRIDE];      // [w][c]   33280 B
    __shared__ __align__(16) __bf16 Rt[RT_ROWS * RSTRIDE];  // [u+48][c] 40960 B

    const int t  = threadIdx.x;
    const int bh = blockIdx.x;
    const int b  = bh >> 7;     // / 128
    const int h  = bh & 127;

    // zero the u-padding rows of Rt once (rows [0,48) and [464,512))
    for (int i = t; i < 96 * RSTRIDE; i += 256) {
        int r  = i / RSTRIDE;
        int cc = i - r * RSTRIDE;
        int row = (r < RPAD) ? r : (r + WSZ);
        Rt[row * RSTRIDE + cc] = (__bf16)0.0f;
    }

    const int wave = t >> 6;
    const int lane = t & 63;
    const int l15  = lane & 15;
    const int l4   = lane >> 4;

    f32x4 acc[7][6];
    #pragma unroll
    for (int ri = 0; ri < 7; ++ri)
        #pragma unroll
        for (int j = 0; j < 6; ++j)
            acc[ri][j] = (f32x4)0.0f;

    const size_t slab = ((size_t)b * CSZ) * (HSZ * WSZ) + (size_t)h * WSZ;
    const float* Lp = left  + slab;
    const float* Rp = right + slab;

    for (int ck = 0; ck < NCHUNK; ++ck) {
        // ---- stage KC=32 channels of L and R, fp32 -> bf16, transposed to [w][c] ----
        // lane map: idx&15 -> w-low (coalesced 64B global runs), (idx>>4)&3 -> c-low
        #pragma unroll 4
        for (int i = 0; i < 52; ++i) {          // 32*416 / 256 = 52
            int idx = i * 256 + t;
            int n0  = idx & 15;
            int clo = (idx >> 4) & 3;
            int q   = idx >> 6;                 // 0..207
            int cl  = ((q & 7) << 2) | clo;     // 0..31
            int w   = ((q >> 3) << 4) | n0;     // 0..415
            int c   = (ck << 5) + cl;
            size_t g = (size_t)c * (HSZ * WSZ) + w;
            float lv = Lp[g];
            float rv = Rp[g];
            Lt[w * RSTRIDE + cl]          = (__bf16)lv;
            Rt[(w + RPAD) * RSTRIDE + cl] = (__bf16)rv;
        }
        __syncthreads();

        // ---- banded GEMM: M[w,u] += sum_c L[c,w] * R[c,u] ----
        #pragma unroll
        for (int ri = 0; ri < 7; ++ri) {
            int row = wave + (ri << 2);
            if (row < 26) {                     // 26 w-tiles of 16, round-robin over 4 waves
                int w0 = row << 4;
                const bf16x8 a = *(const bf16x8*)&Lt[(w0 + l15) * RSTRIDE + (l4 << 3)];
                #pragma unroll
                for (int j = 0; j < 6; ++j) {   // u window [w0-40, w0+55] = 6 tiles
                    int up = w0 - MAXD + (j << 4) + RPAD + l15;
                    const bf16x8 bb = *(const bf16x8*)&Rt[up * RSTRIDE + (l4 << 3)];
                    acc[ri][j] = __builtin_amdgcn_mfma_f32_16x16x32_bf16(a, bb, acc[ri][j], 0, 0, 0);
                }
            }
        }
        __syncthreads();
    }

    // ---- epilogue: D row = w-offset m=(l>>4)*4+r, col = u-offset n=l&15; d = 16j + n - m ----
    const float scale = 1.0f / 256.0f;
    #pragma unroll
    for (int ri = 0; ri < 7; ++ri) {
        int row = wave + (ri << 2);
        if (row < 26) {
            int w0 = row << 4;
            #pragma unroll
            for (int j = 0; j < 6; ++j) {
                #pragma unroll
                for (int r = 0; r < 4; ++r) {
                    int m = (l4 << 2) + r;
                    int d = (j << 4) + l15 - m;
                    if (d >= 0 && d < ND) {
                        int w = w0 + m;
                        out[(((size_t)b * ND + d) * HSZ + h) * WSZ + w] = acc[ri][j][r] * scale;
                    }
                }
            }
        }
    }
}

extern "C" void kernel_launch(void* const* d_in, const int* in_sizes, int n_in,
                              void* d_out, int out_size, void* d_ws, size_t ws_size,
                              hipStream_t stream) {
    const float* left  = (const float*)d_in[0];
    const float* right = (const float*)d_in[1];
    float* out = (float*)d_out;
    (void)in_sizes; (void)n_in; (void)out_size; (void)d_ws; (void)ws_size;
    corr_mfma_kernel<<<dim3(4 * 128), dim3(256), 0, stream>>>(left, right, out);
}